// Round 6
// baseline (245.791 us; speedup 1.0000x reference)
//
#include <hip/hip_runtime.h>

#define D_IN 128
#define BN_EPS 1e-5f
#define BIN_SHIFT 8            // 256 buckets per bin
#define MAXBIN 1024            // supports nTot <= 262144

typedef __attribute__((ext_vector_type(8))) __bf16 bf16x8;
typedef __attribute__((ext_vector_type(8))) unsigned short ushort8;
typedef __attribute__((ext_vector_type(4))) float f32x4;
typedef unsigned short ushort_t;

__device__ inline ushort_t f2bf(float x) {
    union { float f; unsigned u; } c; c.f = x;
    unsigned r = (c.u + 0x7fffu + ((c.u >> 16) & 1u)) >> 16;  // RNE
    return (ushort_t)r;
}
__device__ inline float bf2f(ushort_t x) {
    union { unsigned u; float f; } c; c.u = ((unsigned)x) << 16;
    return c.f;
}
__device__ inline float lof(unsigned v) {
    union { unsigned u; float f; } c; c.u = v << 16;
    return c.f;
}
__device__ inline float hif(unsigned v) {
    union { unsigned u; float f; } c; c.u = v & 0xffff0000u;
    return c.f;
}

// f32 -> bf16 bulk convert for two arrays in one launch, 8 elems/thread
__global__ void cvt2_k(const float* __restrict__ a, const float* __restrict__ b,
                       ushort_t* __restrict__ oa, ushort_t* __restrict__ ob,
                       int n8a, int n8b) {
    int i = blockIdx.x * blockDim.x + threadIdx.x;
    const float* in; ushort_t* out; int k;
    if (i < n8a) { in = a; out = oa; k = i; }
    else if (i < n8a + n8b) { in = b; out = ob; k = i - n8a; }
    else return;
    float4 f0 = ((const float4*)in)[k * 2];
    float4 f1 = ((const float4*)in)[k * 2 + 1];
    ushort8 o;
    o[0] = f2bf(f0.x); o[1] = f2bf(f0.y); o[2] = f2bf(f0.z); o[3] = f2bf(f0.w);
    o[4] = f2bf(f1.x); o[5] = f2bf(f1.y); o[6] = f2bf(f1.z); o[7] = f2bf(f1.w);
    ((ushort8*)out)[k] = o;
}

// ---------------------------------------------------------------------------
// Folded weights (bf16, row-major [term][j][k]) + bias vectors.
// Block 385 zeroes binCnt (tiny hipMemsetAsync costs ~58us under graph).
// ---------------------------------------------------------------------------
__global__ void combine_weights_k(const float* __restrict__ Wn, const float* __restrict__ bn,
                                  const float* __restrict__ Wl, const float* __restrict__ bl,
                                  const float* __restrict__ Wr, const float* __restrict__ Wo,
                                  const float* __restrict__ bo,
                                  ushort_t* __restrict__ Wb, float* __restrict__ c1,
                                  float* __restrict__ c0,
                                  int* __restrict__ binCnt) {
    int b = blockIdx.x;
    int j = threadIdx.x;   // 0..127
    if (b < 384) {
        int term = b >> 7;
        int k = b & 127;
        float acc = 0.f;
        if (term == 0) {
            for (int t = 0; t < 128; ++t) acc += Wo[j * 384 + t] * Wn[t * 128 + k];
        } else if (term == 1) {
            acc = Wo[j * 384 + 128 + k];
            for (int t = 0; t < 128; ++t) acc += Wo[j * 384 + 256 + t] * Wr[t * 128 + k];
        } else {
            for (int t = 0; t < 128; ++t) acc += Wo[j * 384 + 256 + t] * Wl[t * 128 + k];
        }
        Wb[term * 16384 + j * 128 + k] = f2bf(acc);
    } else if (b == 384) {
        float a1 = 0.f, a0 = bo[j];
        for (int t = 0; t < 128; ++t) {
            a1 += Wo[j * 384 + t] * bn[t];
            a0 += Wo[j * 384 + 256 + t] * bl[t];
        }
        c1[j] = a1;
        c0[j] = a0;
    } else {
        for (int i = j; i < MAXBIN; i += 128) binCnt[i] = 0;
    }
}

// ------------------- two-level CSR build (counting sort) -------------------
// pair t: key = t<nE ? dst[t] : nM+src[t-nE];  val = t<nE ? src[t] : dst[t-nE]
// bin = key >> BIN_SHIFT.  packed = (localKey << 20) | val   (val < 2^20)

__global__ __launch_bounds__(256) void bin_hist_k(const int* __restrict__ src,
                                                  const int* __restrict__ dst,
                                                  int* __restrict__ binCnt,
                                                  int nE, int nM, int nBin) {
    __shared__ int h[MAXBIN];
    int t = threadIdx.x;
    for (int i = t; i < nBin; i += 256) h[i] = 0;
    __syncthreads();
    int total = 2 * nE;
    int per = (total + gridDim.x - 1) / gridDim.x;
    int lo = blockIdx.x * per, hi = min(lo + per, total);
    for (int i = lo + t; i < hi; i += 256) {
        int key = (i < nE) ? dst[i] : (nM + src[i - nE]);
        atomicAdd(&h[key >> BIN_SHIFT], 1);
    }
    __syncthreads();
    for (int i = t; i < nBin; i += 256) {
        int v = h[i];
        if (v) atomicAdd(&binCnt[i], v);
    }
}

__global__ __launch_bounds__(1024) void bin_scan_k(const int* __restrict__ binCnt,
                                                   int* __restrict__ binBase,
                                                   int* __restrict__ binCursor,
                                                   int* __restrict__ offs,
                                                   int nBin, int nTot, int total2E) {
    __shared__ int sc[1024];
    int t = threadIdx.x;
    int v = (t < nBin) ? binCnt[t] : 0;
    sc[t] = v;
    __syncthreads();
    for (int off = 1; off < 1024; off <<= 1) {
        int a = (t >= off) ? sc[t - off] : 0;
        __syncthreads();
        sc[t] += a;
        __syncthreads();
    }
    int excl = sc[t] - v;
    if (t <= nBin) binBase[t] = excl;          // binBase[nBin] == total
    if (t < nBin) binCursor[t] = excl;
    if (t == nBin) offs[nTot] = total2E;
}

__global__ __launch_bounds__(256) void bin_scatter_k(const int* __restrict__ src,
                                                     const int* __restrict__ dst,
                                                     int* __restrict__ binCursor,
                                                     unsigned* __restrict__ binned,
                                                     int nE, int nM, int nBin) {
    __shared__ int h[MAXBIN];
    __shared__ int base[MAXBIN];
    int t = threadIdx.x;
    for (int i = t; i < nBin; i += 256) h[i] = 0;
    __syncthreads();
    int total = 2 * nE;
    int per = (total + gridDim.x - 1) / gridDim.x;
    int lo = blockIdx.x * per, hi = min(lo + per, total);
    for (int i = lo + t; i < hi; i += 256) {
        int key = (i < nE) ? dst[i] : (nM + src[i - nE]);
        atomicAdd(&h[key >> BIN_SHIFT], 1);
    }
    __syncthreads();
    for (int i = t; i < nBin; i += 256) {
        int c = h[i];
        base[i] = c ? atomicAdd(&binCursor[i], c) : 0;
        h[i] = 0;  // reuse as local cursor
    }
    __syncthreads();
    for (int i = lo + t; i < hi; i += 256) {
        int key, val;
        if (i < nE) { key = dst[i]; val = src[i]; }
        else        { key = nM + src[i - nE]; val = dst[i - nE]; }
        int b = key >> BIN_SHIFT;
        int p = base[b] + atomicAdd(&h[b], 1);
        binned[p] = ((unsigned)(key & ((1 << BIN_SHIFT) - 1)) << 20) | (unsigned)val;
    }
}

// one workgroup per bin: local counting sort -> offs + list
__global__ __launch_bounds__(256) void bucket_sort_k(const unsigned* __restrict__ binned,
                                                     const int* __restrict__ binBase,
                                                     int* __restrict__ offs,
                                                     int* __restrict__ list, int nTot) {
    __shared__ int hist[256];
    __shared__ int sc[256];
    __shared__ int cur[256];
    int b = blockIdx.x;
    int base = binBase[b], end = binBase[b + 1];
    int n = end - base;
    int t = threadIdx.x;
    hist[t] = 0;
    __syncthreads();
    for (int i = t; i < n; i += 256) atomicAdd(&hist[binned[base + i] >> 20], 1);
    __syncthreads();
    int v = hist[t];
    sc[t] = v;
    __syncthreads();
    for (int off = 1; off < 256; off <<= 1) {
        int a = (t >= off) ? sc[t - off] : 0;
        __syncthreads();
        sc[t] += a;
        __syncthreads();
    }
    int excl = sc[t] - v;
    int bucket = (b << BIN_SHIFT) + t;
    if (bucket < nTot) offs[bucket] = base + excl;
    cur[t] = excl;
    __syncthreads();
    for (int i = t; i < n; i += 256) {
        unsigned p = binned[base + i];
        int lb = p >> 20;
        int pos = atomicAdd(&cur[lb], 1);
        list[base + pos] = (int)(p & 0xFFFFFu);
    }
}

// ------------------------------- gathers -----------------------------------

__global__ __launch_bounds__(256) void gather_xs_k(const uint2* __restrict__ x4,
                                                   const int* __restrict__ offs,
                                                   const int* __restrict__ list,
                                                   uint2* __restrict__ XS4, int nM) {
    int m = blockIdx.x * 8 + (threadIdx.x >> 5);
    if (m >= nM) return;
    int l = threadIdx.x & 31;
    int s = offs[m], e = offs[m + 1];
    float a0 = 0.f, a1 = 0.f, a2 = 0.f, a3 = 0.f;
    for (int s0 = s; s0 < e; s0 += 32) {
        int cnt = min(e - s0, 32);
        int r = (l < cnt) ? list[s0 + l] : 0;
        for (int i0 = 0; i0 < cnt; i0 += 8) {
            uint2 v[8];
#pragma unroll
            for (int j = 0; j < 8; ++j) {
                int idx = i0 + j;
                int cl = idx < cnt ? idx : cnt - 1;
                int rr = __shfl(r, cl, 32);
                v[j] = x4[(size_t)rr * 32 + l];
            }
#pragma unroll
            for (int j = 0; j < 8; ++j) {
                if (i0 + j < cnt) {
                    a0 += lof(v[j].x); a1 += hif(v[j].x);
                    a2 += lof(v[j].y); a3 += hif(v[j].y);
                }
            }
        }
    }
    uint2 o;
    o.x = (unsigned)f2bf(a0) | ((unsigned)f2bf(a1) << 16);
    o.y = (unsigned)f2bf(a2) | ((unsigned)f2bf(a3) << 16);
    XS4[(size_t)m * 32 + l] = o;
}

// H[m][j] = XS[m]@A1.T + XM[m]@A2.T + XM[m-1]@A3.T + deg[m]*c1[j] + c0[j]
// MFMA 16x16x32 bf16; batched register loads (4 A-frags / 8 B-frags in
// flight) to hide L2 latency. BN partial sums stored per block (NO atomics:
// 782-block atomic fan-in onto 1KB serialized at L2 and cost ~40us).
__global__ __launch_bounds__(256) void gemm_h_k(const ushort_t* __restrict__ XSb,
                                                const ushort_t* __restrict__ XMb,
                                                const ushort_t* __restrict__ Wb,
                                                const float* __restrict__ c1,
                                                const float* __restrict__ c0,
                                                const int* __restrict__ off,
                                                ushort_t* __restrict__ Hb,
                                                float* __restrict__ partS,
                                                float* __restrict__ partQ, int nM) {
    __shared__ float lds_s[4][128];
    __shared__ float lds_q[4][128];
    int wave = threadIdx.x >> 6, lane = threadIdx.x & 63;
    int m0 = blockIdx.x * 64 + wave * 16;
    int rl = lane & 15, kg = lane >> 4;
    f32x4 acc[8];
#pragma unroll
    for (int jt = 0; jt < 8; ++jt) acc[jt] = (f32x4){0.f, 0.f, 0.f, 0.f};
    int arow = m0 + rl;
    bool wave_live = (m0 < nM);
    if (wave_live) {
#pragma unroll
        for (int term = 0; term < 3; ++term) {
            const ushort_t* xp = (term == 0) ? XSb : XMb;
            int r2 = (term == 2) ? (arow - 1) : arow;
            bool valid = (r2 >= 0) && (arow < nM);
            const ushort_t* rp = xp + (size_t)r2 * D_IN + kg * 8;
            const ushort_t* wbase = Wb + term * 16384 + rl * 128 + kg * 8;
            // batch the 4 A-fragment loads
            bf16x8 a[4];
#pragma unroll
            for (int kc = 0; kc < 4; ++kc) {
                if (valid) {
                    a[kc] = *reinterpret_cast<const bf16x8*>(rp + kc * 32);
                } else {
#pragma unroll
                    for (int i = 0; i < 8; ++i) a[kc][i] = (__bf16)0.f;
                }
            }
#pragma unroll
            for (int kc = 0; kc < 4; ++kc) {
                // batch the 8 B-fragment loads, then issue the 8 MFMAs
                bf16x8 bfr[8];
#pragma unroll
                for (int jt = 0; jt < 8; ++jt)
                    bfr[jt] = *reinterpret_cast<const bf16x8*>(wbase + jt * 2048 + kc * 32);
#pragma unroll
                for (int jt = 0; jt < 8; ++jt)
                    acc[jt] = __builtin_amdgcn_mfma_f32_16x16x32_bf16(a[kc], bfr[jt], acc[jt], 0, 0, 0);
            }
        }
    }
    float ssum[8], sq[8];
#pragma unroll
    for (int jt = 0; jt < 8; ++jt) { ssum[jt] = 0.f; sq[jt] = 0.f; }
    if (wave_live) {
        float cc1[8], cc0[8];
#pragma unroll
        for (int jt = 0; jt < 8; ++jt) { cc1[jt] = c1[jt * 16 + rl]; cc0[jt] = c0[jt * 16 + rl]; }
#pragma unroll
        for (int r = 0; r < 4; ++r) {
            int rowd = m0 + kg * 4 + r;
            if (rowd < nM) {
                float degv = (float)(off[rowd + 1] - off[rowd]);
                ushort_t* hp = Hb + (size_t)rowd * D_IN;
#pragma unroll
                for (int jt = 0; jt < 8; ++jt) {
                    float hv = acc[jt][r] + degv * cc1[jt] + cc0[jt];
                    hp[jt * 16 + rl] = f2bf(hv);
                    ssum[jt] += hv;
                    sq[jt] += hv * hv;
                }
            }
        }
    }
    // reduce across the 4 kg groups (lanes rl, rl+16, rl+32, rl+48)
#pragma unroll
    for (int jt = 0; jt < 8; ++jt) {
        ssum[jt] += __shfl_xor(ssum[jt], 16, 64);
        ssum[jt] += __shfl_xor(ssum[jt], 32, 64);
        sq[jt]   += __shfl_xor(sq[jt], 16, 64);
        sq[jt]   += __shfl_xor(sq[jt], 32, 64);
    }
    if (lane < 16) {
#pragma unroll
        for (int jt = 0; jt < 8; ++jt) {
            lds_s[wave][jt * 16 + rl] = ssum[jt];
            lds_q[wave][jt * 16 + rl] = sq[jt];
        }
    }
    __syncthreads();
    if (threadIdx.x < 128) {
        int col = threadIdx.x;
        float s = lds_s[0][col] + lds_s[1][col] + lds_s[2][col] + lds_s[3][col];
        float q = lds_q[0][col] + lds_q[1][col] + lds_q[2][col] + lds_q[3][col];
        partS[(size_t)blockIdx.x * 128 + col] = s;
        partQ[(size_t)blockIdx.x * 128 + col] = q;
    }
}

// reduce per-block BN partials -> bnsum/bnsq (single block)
__global__ __launch_bounds__(1024) void bn_reduce_k(const float* __restrict__ partS,
                                                    const float* __restrict__ partQ,
                                                    float* __restrict__ bnsum,
                                                    float* __restrict__ bnsq, int nB) {
    __shared__ float ls[8][128], lq[8][128];
    int col = threadIdx.x & 127, seg = threadIdx.x >> 7;
    float s = 0.f, q = 0.f;
    for (int b = seg; b < nB; b += 8) {
        s += partS[(size_t)b * 128 + col];
        q += partQ[(size_t)b * 128 + col];
    }
    ls[seg][col] = s;
    lq[seg][col] = q;
    __syncthreads();
    if (threadIdx.x < 128) {
        float S = 0.f, Q = 0.f;
#pragma unroll
        for (int i = 0; i < 8; ++i) { S += ls[i][col]; Q += lq[i][col]; }
        bnsum[col] = S;
        bnsq[col] = Q;
    }
}

// out[n] = scale * sum_{e: src==n} H[dst[e]] + cnt * shift   (BN folded inline)
__global__ __launch_bounds__(256) void gather_out_k(const uint2* __restrict__ H4,
                                                    const int* __restrict__ offs2,
                                                    const int* __restrict__ list,
                                                    const float* __restrict__ bnsum,
                                                    const float* __restrict__ bnsq,
                                                    const float* __restrict__ gamma,
                                                    const float* __restrict__ beta,
                                                    float4* __restrict__ out4,
                                                    int nX, int nM) {
    int n = blockIdx.x * 8 + (threadIdx.x >> 5);
    if (n >= nX) return;
    int l = threadIdx.x & 31;
    int s = offs2[n], e = offs2[n + 1];
    float a0 = 0.f, a1 = 0.f, a2 = 0.f, a3 = 0.f;
    for (int s0 = s; s0 < e; s0 += 32) {
        int cnt = min(e - s0, 32);
        int r = (l < cnt) ? list[s0 + l] : 0;
        for (int i0 = 0; i0 < cnt; i0 += 4) {
            uint2 v[4];
#pragma unroll
            for (int j = 0; j < 4; ++j) {
                int idx = i0 + j;
                int cl = idx < cnt ? idx : cnt - 1;
                int rr = __shfl(r, cl, 32);
                v[j] = H4[(size_t)rr * 32 + l];
            }
#pragma unroll
            for (int j = 0; j < 4; ++j) {
                if (i0 + j < cnt) {
                    a0 += lof(v[j].x); a1 += hif(v[j].x);
                    a2 += lof(v[j].y); a3 += hif(v[j].y);
                }
            }
        }
    }
    float4 s1 = ((const float4*)bnsum)[l];
    float4 s2 = ((const float4*)bnsq)[l];
    float4 g  = ((const float4*)gamma)[l];
    float4 be = ((const float4*)beta)[l];
    float inv = 1.0f / (float)nM;
    float cnt = (float)(e - s);
    float4 o;
    {
        float mean = s1.x * inv, var = s2.x * inv - mean * mean;
        float sc = g.x * rsqrtf(var + BN_EPS);
        o.x = sc * a0 + cnt * (be.x - mean * sc);
    }
    {
        float mean = s1.y * inv, var = s2.y * inv - mean * mean;
        float sc = g.y * rsqrtf(var + BN_EPS);
        o.y = sc * a1 + cnt * (be.y - mean * sc);
    }
    {
        float mean = s1.z * inv, var = s2.z * inv - mean * mean;
        float sc = g.z * rsqrtf(var + BN_EPS);
        o.z = sc * a2 + cnt * (be.z - mean * sc);
    }
    {
        float mean = s1.w * inv, var = s2.w * inv - mean * mean;
        float sc = g.w * rsqrtf(var + BN_EPS);
        o.w = sc * a3 + cnt * (be.w - mean * sc);
    }
    out4[(size_t)n * 32 + l] = o;
}

extern "C" void kernel_launch(void* const* d_in, const int* in_sizes, int n_in,
                              void* d_out, int out_size, void* d_ws, size_t ws_size,
                              hipStream_t stream) {
    const float* x_metrical = (const float*)d_in[0];
    const float* x          = (const float*)d_in[1];
    const int*   edge       = (const int*)d_in[2];
    // d_in[3] = batch (unused: all-zero batch branch)
    const float* Wn    = (const float*)d_in[4];
    const float* bn    = (const float*)d_in[5];
    const float* Wl    = (const float*)d_in[6];
    const float* bl    = (const float*)d_in[7];
    const float* Wr    = (const float*)d_in[8];
    const float* Wo    = (const float*)d_in[9];
    const float* bo    = (const float*)d_in[10];
    const float* gamma = (const float*)d_in[11];
    const float* beta  = (const float*)d_in[12];
    float* out = (float*)d_out;

    int nM = in_sizes[0] / D_IN;
    int nX = in_sizes[1] / D_IN;
    int nE = in_sizes[2] / 2;
    int nTot = nM + nX;
    int nBin = (nTot + 255) >> BIN_SHIFT;    // 977 for 250k; must be <= 1024
    int nBlkGemm = (nM + 63) / 64;
    const int* src = edge;        // edge_index[0]
    const int* dst = edge + nE;   // edge_index[1]

    char* ws = (char*)d_ws;
    size_t o = 0;
    auto alloc = [&](size_t bytes) -> void* {
        void* p = ws + o;
        o = (o + bytes + 255) & ~(size_t)255;
        return p;
    };
    ushort_t* Wb        = (ushort_t*)alloc((size_t)3 * 128 * 128 * 2);
    float*    c1        = (float*)alloc(512);
    float*    c0        = (float*)alloc(512);
    float*    bnsum     = (float*)alloc(512);
    float*    bnsq      = (float*)alloc(512);
    int*      binCnt    = (int*)alloc(4096);
    int*      binBase   = (int*)alloc(4104);
    int*      binCursor = (int*)alloc(4096);
    float*    partS     = (float*)alloc((size_t)nBlkGemm * 128 * 4);
    float*    partQ     = (float*)alloc((size_t)nBlkGemm * 128 * 4);
    int*      offs      = (int*)alloc(((size_t)nTot + 1) * 4);
    int*      list      = (int*)alloc((size_t)2 * nE * 4);
    // binned aliases XS: binned dead after bucket_sort_k; XS written after.
    size_t unionSz = (size_t)2 * nE * 4;
    size_t xsSz = (size_t)nM * D_IN * 2;
    char* uregion = (char*)alloc(unionSz > xsSz ? unionSz : xsSz);
    unsigned* binned = (unsigned*)uregion;
    ushort_t* XSb    = (ushort_t*)uregion;
    ushort_t* xmb    = (ushort_t*)alloc((size_t)nM * D_IN * 2);
    ushort_t* xb     = (ushort_t*)alloc((size_t)nX * D_IN * 2);
    // Hb aliases xb: xb dead after gather_xs_k; Hb written by gemm_h_k after.
    ushort_t* Hb     = xb;

    // combine_weights_k block 385 zeroes binCnt (no memsets).
    combine_weights_k<<<386, 128, 0, stream>>>(Wn, bn, Wl, bl, Wr, Wo, bo, Wb, c1, c0,
                                               binCnt);
    {
        int n8x = nX * D_IN / 8, n8m = nM * D_IN / 8;
        cvt2_k<<<(n8x + n8m + 255) / 256, 256, 0, stream>>>(x, x_metrical, xb, xmb, n8x, n8m);
    }
    bin_hist_k<<<256, 256, 0, stream>>>(src, dst, binCnt, nE, nM, nBin);
    bin_scan_k<<<1, 1024, 0, stream>>>(binCnt, binBase, binCursor, offs, nBin, nTot, 2 * nE);
    bin_scatter_k<<<256, 256, 0, stream>>>(src, dst, binCursor, binned, nE, nM, nBin);
    bucket_sort_k<<<nBin, 256, 0, stream>>>(binned, binBase, offs, list, nTot);
    gather_xs_k<<<(nM + 7) / 8, 256, 0, stream>>>((const uint2*)xb, offs, list,
                                                  (uint2*)XSb, nM);
    gemm_h_k<<<nBlkGemm, 256, 0, stream>>>(XSb, xmb, Wb, c1, c0, offs, Hb,
                                           partS, partQ, nM);
    bn_reduce_k<<<1, 1024, 0, stream>>>(partS, partQ, bnsum, bnsq, nBlkGemm);
    gather_out_k<<<(nX + 7) / 8, 256, 0, stream>>>((const uint2*)Hb, offs + nM, list,
                                                   bnsum, bnsq, gamma, beta,
                                                   (float4*)out, nX, nM);
}

// Round 8
// 232.764 us; speedup vs baseline: 1.0560x; 1.0560x over previous
//
#include <hip/hip_runtime.h>

#define D_IN 128
#define BN_EPS 1e-5f
#define BIN_SHIFT 8            // 256 buckets per bin
#define MAXBIN 1024            // supports nTot <= 262144

typedef __attribute__((ext_vector_type(8))) __bf16 bf16x8;
typedef __attribute__((ext_vector_type(8))) unsigned short ushort8;
typedef __attribute__((ext_vector_type(4))) float f32x4;
typedef unsigned short ushort_t;

__device__ inline ushort_t f2bf(float x) {
    union { float f; unsigned u; } c; c.f = x;
    unsigned r = (c.u + 0x7fffu + ((c.u >> 16) & 1u)) >> 16;  // RNE
    return (ushort_t)r;
}
__device__ inline float bf2f(ushort_t x) {
    union { unsigned u; float f; } c; c.u = ((unsigned)x) << 16;
    return c.f;
}
__device__ inline float lof(unsigned v) {
    union { unsigned u; float f; } c; c.u = v << 16;
    return c.f;
}
__device__ inline float hif(unsigned v) {
    union { unsigned u; float f; } c; c.u = v & 0xffff0000u;
    return c.f;
}

// ---------------------------------------------------------------------------
// Folded weights (bf16, row-major [term][j][k]) + bias vectors.
// Block 385 zeroes binCnt (tiny hipMemsetAsync costs ~58us under graph).
// Blocks >= 386: convert x_metrical f32 -> bf16 (fused to avoid a dispatch;
// the x (note) matrix is NOT converted at all — gather_xs reads f32 directly).
// ---------------------------------------------------------------------------
__global__ void combine_weights_k(const float* __restrict__ Wn, const float* __restrict__ bn,
                                  const float* __restrict__ Wl, const float* __restrict__ bl,
                                  const float* __restrict__ Wr, const float* __restrict__ Wo,
                                  const float* __restrict__ bo,
                                  ushort_t* __restrict__ Wb, float* __restrict__ c1,
                                  float* __restrict__ c0,
                                  int* __restrict__ binCnt,
                                  const float* __restrict__ xm, ushort_t* __restrict__ xmb,
                                  int n8m) {
    int b = blockIdx.x;
    int j = threadIdx.x;   // 0..127
    if (b < 384) {
        int term = b >> 7;
        int k = b & 127;
        float acc = 0.f;
        if (term == 0) {
            for (int t = 0; t < 128; ++t) acc += Wo[j * 384 + t] * Wn[t * 128 + k];
        } else if (term == 1) {
            acc = Wo[j * 384 + 128 + k];
            for (int t = 0; t < 128; ++t) acc += Wo[j * 384 + 256 + t] * Wr[t * 128 + k];
        } else {
            for (int t = 0; t < 128; ++t) acc += Wo[j * 384 + 256 + t] * Wl[t * 128 + k];
        }
        Wb[term * 16384 + j * 128 + k] = f2bf(acc);
    } else if (b == 384) {
        float a1 = 0.f, a0 = bo[j];
        for (int t = 0; t < 128; ++t) {
            a1 += Wo[j * 384 + t] * bn[t];
            a0 += Wo[j * 384 + 256 + t] * bl[t];
        }
        c1[j] = a1;
        c0[j] = a0;
    } else if (b == 385) {
        for (int i = j; i < MAXBIN; i += 128) binCnt[i] = 0;
    } else {
        int i = (b - 386) * 128 + j;
        if (i < n8m) {
            float4 f0 = ((const float4*)xm)[i * 2];
            float4 f1 = ((const float4*)xm)[i * 2 + 1];
            ushort8 o;
            o[0] = f2bf(f0.x); o[1] = f2bf(f0.y); o[2] = f2bf(f0.z); o[3] = f2bf(f0.w);
            o[4] = f2bf(f1.x); o[5] = f2bf(f1.y); o[6] = f2bf(f1.z); o[7] = f2bf(f1.w);
            ((ushort8*)xmb)[i] = o;
        }
    }
}

// ------------------- two-level CSR build (counting sort) -------------------
// pair t: key = t<nE ? dst[t] : nM+src[t-nE];  val = t<nE ? src[t] : dst[t-nE]
// bin = key >> BIN_SHIFT.  packed = (localKey << 20) | val   (val < 2^20)

__global__ __launch_bounds__(256) void bin_hist_k(const int* __restrict__ src,
                                                  const int* __restrict__ dst,
                                                  int* __restrict__ binCnt,
                                                  int nE, int nM, int nBin) {
    __shared__ int h[MAXBIN];
    int t = threadIdx.x;
    for (int i = t; i < nBin; i += 256) h[i] = 0;
    __syncthreads();
    int total = 2 * nE;
    int per = (total + gridDim.x - 1) / gridDim.x;
    int lo = blockIdx.x * per, hi = min(lo + per, total);
    for (int i = lo + t; i < hi; i += 256) {
        int key = (i < nE) ? dst[i] : (nM + src[i - nE]);
        atomicAdd(&h[key >> BIN_SHIFT], 1);
    }
    __syncthreads();
    for (int i = t; i < nBin; i += 256) {
        int v = h[i];
        if (v) atomicAdd(&binCnt[i], v);
    }
}

__global__ __launch_bounds__(1024) void bin_scan_k(const int* __restrict__ binCnt,
                                                   int* __restrict__ binBase,
                                                   int* __restrict__ binCursor,
                                                   int* __restrict__ offs,
                                                   int nBin, int nTot, int total2E) {
    __shared__ int sc[1024];
    int t = threadIdx.x;
    int v = (t < nBin) ? binCnt[t] : 0;
    sc[t] = v;
    __syncthreads();
    for (int off = 1; off < 1024; off <<= 1) {
        int a = (t >= off) ? sc[t - off] : 0;
        __syncthreads();
        sc[t] += a;
        __syncthreads();
    }
    int excl = sc[t] - v;
    if (t <= nBin) binBase[t] = excl;          // binBase[nBin] == total
    if (t < nBin) binCursor[t] = excl;
    if (t == nBin) offs[nTot] = total2E;
}

__global__ __launch_bounds__(256) void bin_scatter_k(const int* __restrict__ src,
                                                     const int* __restrict__ dst,
                                                     int* __restrict__ binCursor,
                                                     unsigned* __restrict__ binned,
                                                     int nE, int nM, int nBin) {
    __shared__ int h[MAXBIN];
    __shared__ int base[MAXBIN];
    int t = threadIdx.x;
    for (int i = t; i < nBin; i += 256) h[i] = 0;
    __syncthreads();
    int total = 2 * nE;
    int per = (total + gridDim.x - 1) / gridDim.x;
    int lo = blockIdx.x * per, hi = min(lo + per, total);
    for (int i = lo + t; i < hi; i += 256) {
        int key = (i < nE) ? dst[i] : (nM + src[i - nE]);
        atomicAdd(&h[key >> BIN_SHIFT], 1);
    }
    __syncthreads();
    for (int i = t; i < nBin; i += 256) {
        int c = h[i];
        base[i] = c ? atomicAdd(&binCursor[i], c) : 0;
        h[i] = 0;  // reuse as local cursor
    }
    __syncthreads();
    for (int i = lo + t; i < hi; i += 256) {
        int key, val;
        if (i < nE) { key = dst[i]; val = src[i]; }
        else        { key = nM + src[i - nE]; val = dst[i - nE]; }
        int b = key >> BIN_SHIFT;
        int p = base[b] + atomicAdd(&h[b], 1);
        binned[p] = ((unsigned)(key & ((1 << BIN_SHIFT) - 1)) << 20) | (unsigned)val;
    }
}

// one workgroup per bin: local counting sort -> offs + list
__global__ __launch_bounds__(256) void bucket_sort_k(const unsigned* __restrict__ binned,
                                                     const int* __restrict__ binBase,
                                                     int* __restrict__ offs,
                                                     int* __restrict__ list, int nTot) {
    __shared__ int hist[256];
    __shared__ int sc[256];
    __shared__ int cur[256];
    int b = blockIdx.x;
    int base = binBase[b], end = binBase[b + 1];
    int n = end - base;
    int t = threadIdx.x;
    hist[t] = 0;
    __syncthreads();
    for (int i = t; i < n; i += 256) atomicAdd(&hist[binned[base + i] >> 20], 1);
    __syncthreads();
    int v = hist[t];
    sc[t] = v;
    __syncthreads();
    for (int off = 1; off < 256; off <<= 1) {
        int a = (t >= off) ? sc[t - off] : 0;
        __syncthreads();
        sc[t] += a;
        __syncthreads();
    }
    int excl = sc[t] - v;
    int bucket = (b << BIN_SHIFT) + t;
    if (bucket < nTot) offs[bucket] = base + excl;
    cur[t] = excl;
    __syncthreads();
    for (int i = t; i < n; i += 256) {
        unsigned p = binned[base + i];
        int lb = p >> 20;
        int pos = atomicAdd(&cur[lb], 1);
        list[base + pos] = (int)(p & 0xFFFFFu);
    }
}

// ------------------------------- gathers -----------------------------------

// XS[m] = sum of f32 x rows over edges with dst == m; emit bf16.
// 32 lanes per node (float4 = 4 cols/lane), 8 nodes per block.
__global__ __launch_bounds__(256) void gather_xs_k(const float4* __restrict__ x4,
                                                   const int* __restrict__ offs,
                                                   const int* __restrict__ list,
                                                   uint2* __restrict__ XS4, int nM) {
    int m = blockIdx.x * 8 + (threadIdx.x >> 5);
    if (m >= nM) return;
    int l = threadIdx.x & 31;
    int s = offs[m], e = offs[m + 1];
    float a0 = 0.f, a1 = 0.f, a2 = 0.f, a3 = 0.f;
    for (int s0 = s; s0 < e; s0 += 32) {
        int cnt = min(e - s0, 32);
        int r = (l < cnt) ? list[s0 + l] : 0;
        for (int i0 = 0; i0 < cnt; i0 += 8) {
            float4 v[8];
#pragma unroll
            for (int j = 0; j < 8; ++j) {
                int idx = i0 + j;
                int cl = idx < cnt ? idx : cnt - 1;
                int rr = __shfl(r, cl, 32);
                v[j] = x4[(size_t)rr * 32 + l];
            }
#pragma unroll
            for (int j = 0; j < 8; ++j) {
                if (i0 + j < cnt) {
                    a0 += v[j].x; a1 += v[j].y; a2 += v[j].z; a3 += v[j].w;
                }
            }
        }
    }
    uint2 o;
    o.x = (unsigned)f2bf(a0) | ((unsigned)f2bf(a1) << 16);
    o.y = (unsigned)f2bf(a2) | ((unsigned)f2bf(a3) << 16);
    XS4[(size_t)m * 32 + l] = o;
}

// H[m][j] = XS[m]@A1.T + XM[m]@A2.T + XM[m-1]@A3.T + deg[m]*c1[j] + c0[j]
// MFMA 16x16x32 bf16; batched register loads to hide L2 latency.
// BN partials stored per block (no global atomic fan-in).
__global__ __launch_bounds__(256) void gemm_h_k(const ushort_t* __restrict__ XSb,
                                                const ushort_t* __restrict__ XMb,
                                                const ushort_t* __restrict__ Wb,
                                                const float* __restrict__ c1,
                                                const float* __restrict__ c0,
                                                const int* __restrict__ off,
                                                ushort_t* __restrict__ Hb,
                                                float* __restrict__ partS,
                                                float* __restrict__ partQ, int nM) {
    __shared__ float lds_s[4][128];
    __shared__ float lds_q[4][128];
    int wave = threadIdx.x >> 6, lane = threadIdx.x & 63;
    int m0 = blockIdx.x * 64 + wave * 16;
    int rl = lane & 15, kg = lane >> 4;
    f32x4 acc[8];
#pragma unroll
    for (int jt = 0; jt < 8; ++jt) acc[jt] = (f32x4){0.f, 0.f, 0.f, 0.f};
    int arow = m0 + rl;
    bool wave_live = (m0 < nM);
    if (wave_live) {
#pragma unroll
        for (int term = 0; term < 3; ++term) {
            const ushort_t* xp = (term == 0) ? XSb : XMb;
            int r2 = (term == 2) ? (arow - 1) : arow;
            bool valid = (r2 >= 0) && (arow < nM);
            const ushort_t* rp = xp + (size_t)r2 * D_IN + kg * 8;
            const ushort_t* wbase = Wb + term * 16384 + rl * 128 + kg * 8;
            bf16x8 a[4];
#pragma unroll
            for (int kc = 0; kc < 4; ++kc) {
                if (valid) {
                    a[kc] = *reinterpret_cast<const bf16x8*>(rp + kc * 32);
                } else {
#pragma unroll
                    for (int i = 0; i < 8; ++i) a[kc][i] = (__bf16)0.f;
                }
            }
#pragma unroll
            for (int kc = 0; kc < 4; ++kc) {
                bf16x8 bfr[8];
#pragma unroll
                for (int jt = 0; jt < 8; ++jt)
                    bfr[jt] = *reinterpret_cast<const bf16x8*>(wbase + jt * 2048 + kc * 32);
#pragma unroll
                for (int jt = 0; jt < 8; ++jt)
                    acc[jt] = __builtin_amdgcn_mfma_f32_16x16x32_bf16(a[kc], bfr[jt], acc[jt], 0, 0, 0);
            }
        }
    }
    float ssum[8], sq[8];
#pragma unroll
    for (int jt = 0; jt < 8; ++jt) { ssum[jt] = 0.f; sq[jt] = 0.f; }
    if (wave_live) {
        float cc1[8], cc0[8];
#pragma unroll
        for (int jt = 0; jt < 8; ++jt) { cc1[jt] = c1[jt * 16 + rl]; cc0[jt] = c0[jt * 16 + rl]; }
#pragma unroll
        for (int r = 0; r < 4; ++r) {
            int rowd = m0 + kg * 4 + r;
            if (rowd < nM) {
                float degv = (float)(off[rowd + 1] - off[rowd]);
                ushort_t* hp = Hb + (size_t)rowd * D_IN;
#pragma unroll
                for (int jt = 0; jt < 8; ++jt) {
                    float hv = acc[jt][r] + degv * cc1[jt] + cc0[jt];
                    hp[jt * 16 + rl] = f2bf(hv);
                    ssum[jt] += hv;
                    sq[jt] += hv * hv;
                }
            }
        }
    }
#pragma unroll
    for (int jt = 0; jt < 8; ++jt) {
        ssum[jt] += __shfl_xor(ssum[jt], 16, 64);
        ssum[jt] += __shfl_xor(ssum[jt], 32, 64);
        sq[jt]   += __shfl_xor(sq[jt], 16, 64);
        sq[jt]   += __shfl_xor(sq[jt], 32, 64);
    }
    if (lane < 16) {
#pragma unroll
        for (int jt = 0; jt < 8; ++jt) {
            lds_s[wave][jt * 16 + rl] = ssum[jt];
            lds_q[wave][jt * 16 + rl] = sq[jt];
        }
    }
    __syncthreads();
    if (threadIdx.x < 128) {
        int col = threadIdx.x;
        float s = lds_s[0][col] + lds_s[1][col] + lds_s[2][col] + lds_s[3][col];
        float q = lds_q[0][col] + lds_q[1][col] + lds_q[2][col] + lds_q[3][col];
        partS[(size_t)blockIdx.x * 128 + col] = s;
        partQ[(size_t)blockIdx.x * 128 + col] = q;
    }
}

// reduce per-block BN partials -> bnsum/bnsq (single block)
__global__ __launch_bounds__(1024) void bn_reduce_k(const float* __restrict__ partS,
                                                    const float* __restrict__ partQ,
                                                    float* __restrict__ bnsum,
                                                    float* __restrict__ bnsq, int nB) {
    __shared__ float ls[8][128], lq[8][128];
    int col = threadIdx.x & 127, seg = threadIdx.x >> 7;
    float s = 0.f, q = 0.f;
    for (int b = seg; b < nB; b += 8) {
        s += partS[(size_t)b * 128 + col];
        q += partQ[(size_t)b * 128 + col];
    }
    ls[seg][col] = s;
    lq[seg][col] = q;
    __syncthreads();
    if (threadIdx.x < 128) {
        float S = 0.f, Q = 0.f;
#pragma unroll
        for (int i = 0; i < 8; ++i) { S += ls[i][col]; Q += lq[i][col]; }
        bnsum[col] = S;
        bnsq[col] = Q;
    }
}

// out[n] = scale * sum_{e: src==n} H[dst[e]] + cnt * shift   (BN folded inline)
__global__ __launch_bounds__(256) void gather_out_k(const uint2* __restrict__ H4,
                                                    const int* __restrict__ offs2,
                                                    const int* __restrict__ list,
                                                    const float* __restrict__ bnsum,
                                                    const float* __restrict__ bnsq,
                                                    const float* __restrict__ gamma,
                                                    const float* __restrict__ beta,
                                                    float* __restrict__ out,
                                                    int nX, int nM) {
    int n = blockIdx.x * 8 + (threadIdx.x >> 5);
    if (n >= nX) return;
    int l = threadIdx.x & 31;
    int s = offs2[n], e = offs2[n + 1];
    float a0 = 0.f, a1 = 0.f, a2 = 0.f, a3 = 0.f;
    for (int s0 = s; s0 < e; s0 += 32) {
        int cnt = min(e - s0, 32);
        int r = (l < cnt) ? list[s0 + l] : 0;
        for (int i0 = 0; i0 < cnt; i0 += 4) {
            uint2 v[4];
#pragma unroll
            for (int j = 0; j < 4; ++j) {
                int idx = i0 + j;
                int cl = idx < cnt ? idx : cnt - 1;
                int rr = __shfl(r, cl, 32);
                v[j] = H4[(size_t)rr * 32 + l];
            }
#pragma unroll
            for (int j = 0; j < 4; ++j) {
                if (i0 + j < cnt) {
                    a0 += lof(v[j].x); a1 += hif(v[j].x);
                    a2 += lof(v[j].y); a3 += hif(v[j].y);
                }
            }
        }
    }
    float4 s1 = ((const float4*)bnsum)[l];
    float4 s2 = ((const float4*)bnsq)[l];
    float4 g  = ((const float4*)gamma)[l];
    float4 be = ((const float4*)beta)[l];
    float inv = 1.0f / (float)nM;
    float cnt = (float)(e - s);
    f32x4 o;
    {
        float mean = s1.x * inv, var = s2.x * inv - mean * mean;
        float sc = g.x * rsqrtf(var + BN_EPS);
        o.x = sc * a0 + cnt * (be.x - mean * sc);
    }
    {
        float mean = s1.y * inv, var = s2.y * inv - mean * mean;
        float sc = g.y * rsqrtf(var + BN_EPS);
        o.y = sc * a1 + cnt * (be.y - mean * sc);
    }
    {
        float mean = s1.z * inv, var = s2.z * inv - mean * mean;
        float sc = g.z * rsqrtf(var + BN_EPS);
        o.z = sc * a2 + cnt * (be.z - mean * sc);
    }
    {
        float mean = s1.w * inv, var = s2.w * inv - mean * mean;
        float sc = g.w * rsqrtf(var + BN_EPS);
        o.w = sc * a3 + cnt * (be.w - mean * sc);
    }
    // non-temporal: keep the 102MB output stream from evicting L3-resident H/x
    __builtin_nontemporal_store(o, (f32x4*)(out + (size_t)n * 128 + l * 4));
}

extern "C" void kernel_launch(void* const* d_in, const int* in_sizes, int n_in,
                              void* d_out, int out_size, void* d_ws, size_t ws_size,
                              hipStream_t stream) {
    const float* x_metrical = (const float*)d_in[0];
    const float* x          = (const float*)d_in[1];
    const int*   edge       = (const int*)d_in[2];
    // d_in[3] = batch (unused: all-zero batch branch)
    const float* Wn    = (const float*)d_in[4];
    const float* bn    = (const float*)d_in[5];
    const float* Wl    = (const float*)d_in[6];
    const float* bl    = (const float*)d_in[7];
    const float* Wr    = (const float*)d_in[8];
    const float* Wo    = (const float*)d_in[9];
    const float* bo    = (const float*)d_in[10];
    const float* gamma = (const float*)d_in[11];
    const float* beta  = (const float*)d_in[12];
    float* out = (float*)d_out;

    int nM = in_sizes[0] / D_IN;
    int nX = in_sizes[1] / D_IN;
    int nE = in_sizes[2] / 2;
    int nTot = nM + nX;
    int nBin = (nTot + 255) >> BIN_SHIFT;    // 977 for 250k; must be <= 1024
    int nBlkGemm = (nM + 63) / 64;
    const int* src = edge;        // edge_index[0]
    const int* dst = edge + nE;   // edge_index[1]

    char* ws = (char*)d_ws;
    size_t o = 0;
    auto alloc = [&](size_t bytes) -> void* {
        void* p = ws + o;
        o = (o + bytes + 255) & ~(size_t)255;
        return p;
    };
    ushort_t* Wb        = (ushort_t*)alloc((size_t)3 * 128 * 128 * 2);
    float*    c1        = (float*)alloc(512);
    float*    c0        = (float*)alloc(512);
    float*    bnsum     = (float*)alloc(512);
    float*    bnsq      = (float*)alloc(512);
    int*      binCnt    = (int*)alloc(4096);
    int*      binBase   = (int*)alloc(4104);
    int*      binCursor = (int*)alloc(4096);
    float*    partS     = (float*)alloc((size_t)nBlkGemm * 128 * 4);
    float*    partQ     = (float*)alloc((size_t)nBlkGemm * 128 * 4);
    int*      offs      = (int*)alloc(((size_t)nTot + 1) * 4);
    int*      list      = (int*)alloc((size_t)2 * nE * 4);
    // binned aliases XS: binned dead after bucket_sort_k; XS written after.
    size_t unionSz = (size_t)2 * nE * 4;
    size_t xsSz = (size_t)nM * D_IN * 2;
    char* uregion = (char*)alloc(unionSz > xsSz ? unionSz : xsSz);
    unsigned* binned = (unsigned*)uregion;
    ushort_t* XSb    = (ushort_t*)uregion;
    ushort_t* xmb    = (ushort_t*)alloc((size_t)nM * D_IN * 2);
    ushort_t* Hb     = (ushort_t*)alloc((size_t)nM * D_IN * 2);

    int n8m = nM * D_IN / 8;
    int nBlkComb = 386 + (n8m + 127) / 128;
    // combine_weights_k: folded weights + binCnt zero + x_metrical bf16 cvt.
    combine_weights_k<<<nBlkComb, 128, 0, stream>>>(Wn, bn, Wl, bl, Wr, Wo, bo, Wb, c1, c0,
                                                    binCnt, x_metrical, xmb, n8m);
    bin_hist_k<<<256, 256, 0, stream>>>(src, dst, binCnt, nE, nM, nBin);
    bin_scan_k<<<1, 1024, 0, stream>>>(binCnt, binBase, binCursor, offs, nBin, nTot, 2 * nE);
    bin_scatter_k<<<256, 256, 0, stream>>>(src, dst, binCursor, binned, nE, nM, nBin);
    bucket_sort_k<<<nBin, 256, 0, stream>>>(binned, binBase, offs, list, nTot);
    gather_xs_k<<<(nM + 7) / 8, 256, 0, stream>>>((const float4*)x, offs, list,
                                                  (uint2*)XSb, nM);
    gemm_h_k<<<nBlkGemm, 256, 0, stream>>>(XSb, xmb, Wb, c1, c0, offs, Hb,
                                           partS, partQ, nM);
    bn_reduce_k<<<1, 1024, 0, stream>>>(partS, partQ, bnsum, bnsq, nBlkGemm);
    gather_out_k<<<(nX + 7) / 8, 256, 0, stream>>>((const uint2*)Hb, offs + nM, list,
                                                   bnsum, bnsq, gamma, beta,
                                                   out, nX, nM);
}